// Round 1
// baseline (262.586 us; speedup 1.0000x reference)
//
#include <hip/hip_runtime.h>

// Patch_Embed_Center_Rotate: x (256,3,224,224) f32, P=16, grid 14x14.
// out = x everywhere, except patches with grid col j in [5,9] AND grid row
// k in [5,9], which are transposed within the 16x16 patch:
//   out[b,c, k*16+a3, j*16+a4] = x[b,c, k*16+a4, j*16+a3]
//
// v2 strategy: block-per-strip. Each block owns one (b*c, k) strip of
// 16 rows x 224 cols = 14336 contiguous bytes.
//  - non-center strips (k not in [5,9], 9 of 14): pure float4 copy, fully
//    coalesced, zero divergence.
//  - center strips: copy the 36 non-center float4 cols per row directly;
//    stage the 16x80 center region through LDS with transpose-on-write
//    (scalar LDS ops, odd stride 81 to spread banks), then emit float4
//    coalesced stores.
// This removes v1's stride-896B scalar global reads (4 per float4, ~200cyc
// L2-hit latency each) in the center region, which serialized VMEM and
// dragged the whole kernel to ~1.2 TB/s (252.9 us vs ~47 us roofline).

#define WW 224
#define W4 56                // float4 cols per row
#define PP 16
#define NSTRIP_F4 (PP * W4)  // 896 float4 per strip
#define LDS_S 81             // odd row stride: a3-scatter writes hit banks
                             // (a3*17 mod 32) -> all distinct for a3 step 4

__global__ __launch_bounds__(256) void patch_rotate_kernel(
    const float* __restrict__ x, float* __restrict__ out) {
  const int bid = blockIdx.x;
  const int k  = bid % 14;      // grid row
  const int bc = bid / 14;      // fused (b,c), 0..767
  const int stripBase = (bc * WW + k * PP) * WW;  // in floats, 16B-aligned
  const float4* __restrict__ xs = (const float4*)(x + stripBase);
  float4* __restrict__ os = (float4*)(out + stripBase);
  const int tid = threadIdx.x;

  if (k < 5 || k > 9) {
    // identity strip: 896 contiguous float4
    for (int i = tid; i < NSTRIP_F4; i += 256) os[i] = xs[i];
    return;
  }

  __shared__ float ldsT[PP * LDS_S];  // out-ordered center region, 5184 B

  // phase 1: load center 16x80 (float4-coalesced), scatter into LDS
  // transposed within each 16x16 patch: ldsT[ac][jl*16+ar] = X[ar][jl*16+ac]
  for (int i = tid; i < PP * 20; i += 256) {
    const int ar = i / 20;             // source row within strip (= out a4)
    const int c4 = i % 20;             // float4 col within center region
    const float4 v = xs[ar * W4 + 20 + c4];
    const int jl  = c4 >> 2;           // local patch 0..4
    const int ac0 = (c4 & 3) << 2;     // source col within patch (= out a3)
    const int cb  = jl * PP + ar;      // out col within center region
    ldsT[(ac0 + 0) * LDS_S + cb] = v.x;
    ldsT[(ac0 + 1) * LDS_S + cb] = v.y;
    ldsT[(ac0 + 2) * LDS_S + cb] = v.z;
    ldsT[(ac0 + 3) * LDS_S + cb] = v.w;
  }

  // phase 2 (independent, overlaps LDS latency): copy non-center cols.
  // 36 float4 per row (cols 0..19 and 40..55), 16 rows.
  for (int i = tid; i < PP * 36; i += 256) {
    const int r  = i / 36;
    const int cc = i % 36;
    const int c4 = cc < 20 ? cc : cc + 20;
    os[r * W4 + c4] = xs[r * W4 + c4];
  }

  __syncthreads();

  // phase 3: emit center region, coalesced float4 stores from LDS rows.
  for (int i = tid; i < PP * 20; i += 256) {
    const int a3 = i / 20;
    const int c4 = i % 20;
    const float* row = ldsT + a3 * LDS_S + c4 * 4;
    float4 v;
    v.x = row[0]; v.y = row[1]; v.z = row[2]; v.w = row[3];
    os[a3 * W4 + 20 + c4] = v;
  }
}

extern "C" void kernel_launch(void* const* d_in, const int* in_sizes, int n_in,
                              void* d_out, int out_size, void* d_ws, size_t ws_size,
                              hipStream_t stream) {
  const float* x = (const float*)d_in[0];
  float* out = (float*)d_out;
  const int blocks = 768 * 14;  // one block per (b*c, grid-row) strip
  patch_rotate_kernel<<<blocks, 256, 0, stream>>>(x, out);
}